// Round 3
// baseline (7758.250 us; speedup 1.0000x reference)
//
#include <hip/hip_runtime.h>
#include <hip/hip_bf16.h>

#define BB 4
#define SS 1024
#define PP 1024
#define EE 1024
#define HH 16
#define DD 64
#define NS 2048          // P + S
#define E3 3072
#define VOFF 8388608     // element offset of V section in present [2,B,H,NS,D]
#define VPAST 4194304    // element offset of V section in layer_past [2,B,H,P,D]

typedef __attribute__((ext_vector_type(8))) short short8;
typedef __attribute__((ext_vector_type(4))) float floatx4;

__device__ __forceinline__ short f2bf(float f) {
    return (short)(__bfloat16_as_ushort(__float2bfloat16(f)));
}

// ---------------- GEMM: dst = A[M,K] @ W[K,N] + bias (f32 in, bf16 MFMA, f32 out) ----
// MODE 0 (QKV): A = x [4096,1024]; epilogue scatters into present (f32):
//   cols [0,1K)  q     -> present[0,b,h,s,d]        (k-past stash)
//   cols [1K,2K) k_new -> present[0,b,h,1024+s,d]
//   cols [2K,3K) v_new -> present[1,b,h,1024+s,d]
// MODE 1 (proj): A = am read from v-past stash present[1,b,h,q,d]; plain store.
template<int MODE>
__global__ __launch_bounds__(256) void gemm_k(
    const float* __restrict__ A,
    const float* __restrict__ W,
    const float* __restrict__ bias,
    float* __restrict__ dst,
    int N, int K)
{
    __shared__ __align__(16) short As[64][32];
    __shared__ __align__(16) short Bs[64][40];   // 80B rows (16 | 80): aligned frag reads
    int tid = threadIdx.x;
    int wave = tid >> 6, lane = tid & 63;
    int m0 = blockIdx.x * 64, n0 = blockIdx.y * 64;

    floatx4 acc[4];
#pragma unroll
    for (int c = 0; c < 4; ++c) acc[c] = (floatx4){0.f, 0.f, 0.f, 0.f};

    int lr = tid >> 2, lc = (tid & 3) * 8;    // A staging: 64 rows x 32 k
    int kr = tid >> 3, nc = (tid & 7) * 8;    // W staging: 32 k-rows x 64 n
    const int fr = lane & 15;
    const int kb = lane >> 4;

    for (int k0 = 0; k0 < K; k0 += 32) {
        __syncthreads();
        {   // stage A tile (f32 -> bf16)
            int arow = m0 + lr, acol = k0 + lc;
            size_t aoff;
            if (MODE == 0) {
                aoff = (size_t)arow * K + acol;
            } else {
                aoff = (size_t)VOFF +
                       (((size_t)(arow >> 10) * HH + (acol >> 6)) * NS + (arow & 1023)) * DD +
                       (acol & 63);
            }
            float4 a0 = *(const float4*)(A + aoff);
            float4 a1 = *(const float4*)(A + aoff + 4);
            short8 s8;
            s8[0] = f2bf(a0.x); s8[1] = f2bf(a0.y); s8[2] = f2bf(a0.z); s8[3] = f2bf(a0.w);
            s8[4] = f2bf(a1.x); s8[5] = f2bf(a1.y); s8[6] = f2bf(a1.z); s8[7] = f2bf(a1.w);
            *(short8*)(&As[lr][lc]) = s8;
        }
        {   // stage W tile transposed (f32 -> bf16): Bs[n][k]
            size_t woff = (size_t)(k0 + kr) * N + n0 + nc;
            float4 w0 = *(const float4*)(W + woff);
            float4 w1 = *(const float4*)(W + woff + 4);
            Bs[nc + 0][kr] = f2bf(w0.x); Bs[nc + 1][kr] = f2bf(w0.y);
            Bs[nc + 2][kr] = f2bf(w0.z); Bs[nc + 3][kr] = f2bf(w0.w);
            Bs[nc + 4][kr] = f2bf(w1.x); Bs[nc + 5][kr] = f2bf(w1.y);
            Bs[nc + 6][kr] = f2bf(w1.z); Bs[nc + 7][kr] = f2bf(w1.w);
        }
        __syncthreads();
        short8 af = *(const short8*)(&As[wave * 16 + fr][kb * 8]);
#pragma unroll
        for (int c = 0; c < 4; ++c) {
            short8 bf = *(const short8*)(&Bs[c * 16 + fr][kb * 8]);
            acc[c] = __builtin_amdgcn_mfma_f32_16x16x32_bf16(af, bf, acc[c], 0, 0, 0);
        }
    }
    // epilogue: C/D layout col=lane&15, row=(lane>>4)*4+reg  [verified m89]
#pragma unroll
    for (int c = 0; c < 4; ++c) {
        int gc = n0 + c * 16 + fr;
        float bv = bias[gc];
#pragma unroll
        for (int r = 0; r < 4; ++r) {
            int gr = m0 + wave * 16 + kb * 4 + r;
            float val = acc[c][r] + bv;
            if (MODE == 1) {
                dst[(size_t)gr * N + gc] = val;
            } else {
                int sec = gc >> 10, h = (gc >> 6) & 15, d = gc & 63;
                int b = gr >> 10, sq = gr & 1023;
                size_t bh = (size_t)(b * HH + h);
                size_t off;
                if (sec == 0)      off = (bh * NS + sq) * DD + d;               // q stash
                else if (sec == 1) off = (bh * NS + PP + sq) * DD + d;          // k_new
                else               off = VOFF + (bh * NS + PP + sq) * DD + d;   // v_new
                dst[off] = val;
            }
        }
    }
}

// ---------------- attention: one wave per query (all f32) ----------------
__global__ __launch_bounds__(128) void attention_k(
    const float* __restrict__ past,   // layer_past [2,B,H,P,D]
    float* __restrict__ present)      // q in k-past stash; am out to v-past stash
{
    __shared__ float red[2][64][65];
    int wave = threadIdx.x >> 6, lane = threadIdx.x & 63;
    int qlin = blockIdx.x * 2 + wave;          // (b*H + h)*S + q
    int q = qlin & (SS - 1);
    int h = (qlin >> 10) & (HH - 1);
    int b = qlin >> 14;
    size_t bh = (size_t)(b * HH + h);

    const float* qptr = present + (bh * NS + q) * DD;
    float qr[64];
#pragma unroll
    for (int j = 0; j < 16; ++j) {
        float4 v = *(const float4*)(qptr + j * 4);
        qr[j * 4 + 0] = v.x * 0.125f; qr[j * 4 + 1] = v.y * 0.125f;  // 1/sqrt(D)
        qr[j * 4 + 2] = v.z * 0.125f; qr[j * 4 + 3] = v.w * 0.125f;
    }
    const float* kpast = past + bh * PP * DD;
    const float* vpast = past + VPAST + bh * PP * DD;
    const float* knew  = present + bh * NS * DD;          // index by t (>=1024)
    const float* vnew  = present + VOFF + bh * NS * DD;

    int tmax = PP + q;
    float s[32];
    float m = -1e30f;
#pragma unroll
    for (int i = 0; i < 32; ++i) {
        int t = lane + i * 64;
        const float* kr = (i < 16) ? (kpast + (size_t)t * DD)
                                   : (knew + (size_t)t * DD);
        float dot = 0.f;
#pragma unroll
        for (int j = 0; j < 16; ++j) {
            float4 v = *(const float4*)(kr + j * 4);
            dot += qr[j*4+0]*v.x + qr[j*4+1]*v.y + qr[j*4+2]*v.z + qr[j*4+3]*v.w;
        }
        s[i] = (i < 16) ? dot : ((t <= tmax) ? dot : -1e30f);
        m = fmaxf(m, s[i]);
    }
#pragma unroll
    for (int off = 32; off >= 1; off >>= 1) m = fmaxf(m, __shfl_xor(m, off, 64));
    float lsum = 0.f;
#pragma unroll
    for (int i = 0; i < 32; ++i) {
        s[i] = exp2f((s[i] - m) * 1.44269504f);
        lsum += s[i];
    }
#pragma unroll
    for (int off = 32; off >= 1; off >>= 1) lsum += __shfl_xor(lsum, off, 64);
    float inv = 1.f / lsum;

    float acc[64];
#pragma unroll
    for (int d = 0; d < 64; ++d) acc[d] = 0.f;
#pragma unroll
    for (int i = 0; i < 32; ++i) {
        float p = s[i];
        int t = lane + i * 64;
        const float* vr = (i < 16) ? (vpast + (size_t)t * DD)
                                   : (vnew + (size_t)t * DD);
#pragma unroll
        for (int j = 0; j < 16; ++j) {
            float4 v = *(const float4*)(vr + j * 4);
            acc[j*4+0] += p * v.x; acc[j*4+1] += p * v.y;
            acc[j*4+2] += p * v.z; acc[j*4+3] += p * v.w;
        }
    }
#pragma unroll
    for (int d = 0; d < 64; ++d) red[wave][lane][d] = acc[d];
    __syncthreads();
    float outv = 0.f;
#pragma unroll
    for (int L = 0; L < 64; ++L) outv += red[wave][L][lane];
    outv *= inv;
    present[VOFF + (bh * NS + q) * DD + lane] = outv;   // am -> v-past stash
}

// ---------------- final: copy layer_past into present's past slots ----------------
__global__ __launch_bounds__(256) void copy_past_k(
    const float* __restrict__ past,   // [2,B,H,P,D] flat
    float* __restrict__ present)      // [2,B,H,NS,D]
{
    int idx = blockIdx.x * 256 + threadIdx.x;  // 1,048,576 threads x 8 elems
    size_t e0 = (size_t)idx * 8;
    int r = (int)(e0 >> 6);          // row in [0, 2*B*H*P) = 131072
    int off = (int)(e0 & 63);
    int t = r & (PP - 1);
    int bh = r >> 10;                // [kv*64 + b*16 + h]
    size_t dstoff = (((size_t)bh * NS) + t) * DD + off;
    *(float4*)(present + dstoff)     = *(const float4*)(past + e0);
    *(float4*)(present + dstoff + 4) = *(const float4*)(past + e0 + 4);
}

extern "C" void kernel_launch(void* const* d_in, const int* in_sizes, int n_in,
                              void* d_out, int out_size, void* d_ws, size_t ws_size,
                              hipStream_t stream) {
    const float* x      = (const float*)d_in[0];
    const float* past   = (const float*)d_in[1];
    const float* w_attn = (const float*)d_in[2];
    const float* b_attn = (const float*)d_in[3];
    const float* w_proj = (const float*)d_in[4];
    const float* b_proj = (const float*)d_in[5];
    float* out = (float*)d_out;
    float* present = out + (size_t)BB * SS * EE;   // d_out as scratch; d_ws unused

    // 1. QKV GEMM: q -> k-past stash, k_new/v_new -> final present slots
    gemm_k<0><<<dim3(BB * SS / 64, E3 / 64), 256, 0, stream>>>(x, w_attn, b_attn, present, E3, EE);
    // 2. attention: past K/V from d_in, new K/V + q from present; am -> v-past stash
    attention_k<<<(BB * HH * SS) / 2, 128, 0, stream>>>(past, present);
    // 3. proj GEMM: reads am from v-past stash, writes out region
    gemm_k<1><<<dim3(BB * SS / 64, EE / 64), 256, 0, stream>>>(present, w_proj, b_proj, out, EE, EE);
    // 4. overwrite both stashes with the real past
    copy_past_k<<<(2 * BB * HH * PP * DD) / (256 * 8), 256, 0, stream>>>(past, present);
}

// Round 4
// 453.486 us; speedup vs baseline: 17.1080x; 17.1080x over previous
//
#include <hip/hip_runtime.h>
#include <hip/hip_bf16.h>

#define BB 4
#define SS 1024
#define PP 1024
#define EE 1024
#define HH 16
#define DD 64
#define NS 2048          // P + S
#define E3 3072
#define VOFF 8388608     // element offset of V section in present [2,B,H,NS,D]
#define VPAST 4194304    // element offset of V section in layer_past [2,B,H,P,D]

typedef __attribute__((ext_vector_type(8))) short short8;
typedef __attribute__((ext_vector_type(4))) float floatx4;

__device__ __forceinline__ short f2bf(float f) {
    return (short)(__bfloat16_as_ushort(__float2bfloat16(f)));
}

// ---------------- GEMM: dst = A[M,K] @ W[K,N] + bias (f32 in, bf16 MFMA, f32 out) ----
template<int MODE>
__global__ __launch_bounds__(256) void gemm_k(
    const float* __restrict__ A,
    const float* __restrict__ W,
    const float* __restrict__ bias,
    float* __restrict__ dst,
    int N, int K)
{
    __shared__ __align__(16) short As[64][32];
    __shared__ __align__(16) short Bs[64][40];
    int tid = threadIdx.x;
    int wave = tid >> 6, lane = tid & 63;
    int m0 = blockIdx.x * 64, n0 = blockIdx.y * 64;

    floatx4 acc[4];
#pragma unroll
    for (int c = 0; c < 4; ++c) acc[c] = (floatx4){0.f, 0.f, 0.f, 0.f};

    int lr = tid >> 2, lc = (tid & 3) * 8;
    int kr = tid >> 3, nc = (tid & 7) * 8;
    const int fr = lane & 15;
    const int kb = lane >> 4;

    for (int k0 = 0; k0 < K; k0 += 32) {
        __syncthreads();
        {
            int arow = m0 + lr, acol = k0 + lc;
            size_t aoff;
            if (MODE == 0) {
                aoff = (size_t)arow * K + acol;
            } else {
                aoff = (size_t)VOFF +
                       (((size_t)(arow >> 10) * HH + (acol >> 6)) * NS + (arow & 1023)) * DD +
                       (acol & 63);
            }
            float4 a0 = *(const float4*)(A + aoff);
            float4 a1 = *(const float4*)(A + aoff + 4);
            short8 s8;
            s8[0] = f2bf(a0.x); s8[1] = f2bf(a0.y); s8[2] = f2bf(a0.z); s8[3] = f2bf(a0.w);
            s8[4] = f2bf(a1.x); s8[5] = f2bf(a1.y); s8[6] = f2bf(a1.z); s8[7] = f2bf(a1.w);
            *(short8*)(&As[lr][lc]) = s8;
        }
        {
            size_t woff = (size_t)(k0 + kr) * N + n0 + nc;
            float4 w0 = *(const float4*)(W + woff);
            float4 w1 = *(const float4*)(W + woff + 4);
            Bs[nc + 0][kr] = f2bf(w0.x); Bs[nc + 1][kr] = f2bf(w0.y);
            Bs[nc + 2][kr] = f2bf(w0.z); Bs[nc + 3][kr] = f2bf(w0.w);
            Bs[nc + 4][kr] = f2bf(w1.x); Bs[nc + 5][kr] = f2bf(w1.y);
            Bs[nc + 6][kr] = f2bf(w1.z); Bs[nc + 7][kr] = f2bf(w1.w);
        }
        __syncthreads();
        short8 af = *(const short8*)(&As[wave * 16 + fr][kb * 8]);
#pragma unroll
        for (int c = 0; c < 4; ++c) {
            short8 bf = *(const short8*)(&Bs[c * 16 + fr][kb * 8]);
            acc[c] = __builtin_amdgcn_mfma_f32_16x16x32_bf16(af, bf, acc[c], 0, 0, 0);
        }
    }
#pragma unroll
    for (int c = 0; c < 4; ++c) {
        int gc = n0 + c * 16 + fr;
        float bv = bias[gc];
#pragma unroll
        for (int r = 0; r < 4; ++r) {
            int gr = m0 + wave * 16 + kb * 4 + r;
            float val = acc[c][r] + bv;
            if (MODE == 1) {
                dst[(size_t)gr * N + gc] = val;
            } else {
                int sec = gc >> 10, h = (gc >> 6) & 15, d = gc & 63;
                int b = gr >> 10, sq = gr & 1023;
                size_t bh = (size_t)(b * HH + h);
                size_t off;
                if (sec == 0)      off = (bh * NS + sq) * DD + d;               // q stash
                else if (sec == 1) off = (bh * NS + PP + sq) * DD + d;          // k_new
                else               off = VOFF + (bh * NS + PP + sq) * DD + d;   // v_new
                dst[off] = val;
            }
        }
    }
}

// ---------------- flash attention: 64 queries/block, MFMA QK^T and PV ----------------
__global__ __launch_bounds__(256) void flash_attn_k(
    const float* __restrict__ past,   // layer_past [2,B,H,P,D]
    float* __restrict__ present)      // q in k-past stash; am out to v-past stash
{
    __shared__ __align__(16) short Ks[64][72];       // [key][d]
    __shared__ __align__(16) short Vs[64][72];       // transposed: [d][key]
    __shared__ __align__(16) short Ps[4][16][72];    // per-wave P round-trip

    int tid = threadIdx.x;
    int wave = tid >> 6, lane = tid & 63;
    int fr = lane & 15, quad = lane >> 4;
    int bh = blockIdx.x >> 4;               // b*H + h  (slow index: L2 reuse of K/V)
    int q0 = (blockIdx.x & 15) * 64;
    size_t bhNS = (size_t)bh * NS;

    // Q A-fragments (row m = fr), scale 1/sqrt(D)=0.125 folded in (exact in bf16)
    const float* qrow = present + (bhNS + q0 + wave * 16 + fr) * DD;
    short8 qf[2];
#pragma unroll
    for (int ks = 0; ks < 2; ++ks) {
        const float* p = qrow + ks * 32 + quad * 8;
        float4 a0 = *(const float4*)(p);
        float4 a1 = *(const float4*)(p + 4);
        short8 s8;
        s8[0] = f2bf(a0.x * 0.125f); s8[1] = f2bf(a0.y * 0.125f);
        s8[2] = f2bf(a0.z * 0.125f); s8[3] = f2bf(a0.w * 0.125f);
        s8[4] = f2bf(a1.x * 0.125f); s8[5] = f2bf(a1.y * 0.125f);
        s8[6] = f2bf(a1.z * 0.125f); s8[7] = f2bf(a1.w * 0.125f);
        qf[ks] = s8;
    }

    const float* kpast = past + (size_t)bh * PP * DD;
    const float* vpast = past + VPAST + (size_t)bh * PP * DD;
    const float* knew  = present + bhNS * DD;           // index by absolute t >= 1024
    const float* vnew  = present + VOFF + bhNS * DD;

    float m_r[4], l_r[4];
    floatx4 Oacc[4];
#pragma unroll
    for (int r = 0; r < 4; ++r) { m_r[r] = -1e30f; l_r[r] = 0.f; }
#pragma unroll
    for (int c2 = 0; c2 < 4; ++c2) Oacc[c2] = (floatx4){0.f, 0.f, 0.f, 0.f};

    int skey = tid >> 2, sd = (tid & 3) * 16;   // K staging: row, d-offset
    int vkey = tid & 63, vd0 = (tid >> 6) * 16; // V staging: key, d-block

    int nchunks = 17 + (q0 >> 6);
    for (int c = 0; c < nchunks; ++c) {
        int t0 = c * 64;
        const float* kc = (t0 < PP) ? (kpast + (size_t)t0 * DD) : (knew + (size_t)t0 * DD);
        const float* vc = (t0 < PP) ? (vpast + (size_t)t0 * DD) : (vnew + (size_t)t0 * DD);
        __syncthreads();
        {   // stage K chunk: [64 key][64 d] f32 -> bf16, natural layout
            const float* src = kc + (size_t)skey * DD + sd;
            float4 a0 = *(const float4*)(src);
            float4 a1 = *(const float4*)(src + 4);
            float4 a2 = *(const float4*)(src + 8);
            float4 a3 = *(const float4*)(src + 12);
            short8 s0, s1;
            s0[0]=f2bf(a0.x); s0[1]=f2bf(a0.y); s0[2]=f2bf(a0.z); s0[3]=f2bf(a0.w);
            s0[4]=f2bf(a1.x); s0[5]=f2bf(a1.y); s0[6]=f2bf(a1.z); s0[7]=f2bf(a1.w);
            s1[0]=f2bf(a2.x); s1[1]=f2bf(a2.y); s1[2]=f2bf(a2.z); s1[3]=f2bf(a2.w);
            s1[4]=f2bf(a3.x); s1[5]=f2bf(a3.y); s1[6]=f2bf(a3.z); s1[7]=f2bf(a3.w);
            *(short8*)(&Ks[skey][sd]) = s0;
            *(short8*)(&Ks[skey][sd + 8]) = s1;
        }
        {   // stage V chunk transposed: Vs[d][key]
            const float* src = vc + (size_t)vkey * DD + vd0;
            float4 a0 = *(const float4*)(src);
            float4 a1 = *(const float4*)(src + 4);
            float4 a2 = *(const float4*)(src + 8);
            float4 a3 = *(const float4*)(src + 12);
            Vs[vd0+ 0][vkey]=f2bf(a0.x); Vs[vd0+ 1][vkey]=f2bf(a0.y);
            Vs[vd0+ 2][vkey]=f2bf(a0.z); Vs[vd0+ 3][vkey]=f2bf(a0.w);
            Vs[vd0+ 4][vkey]=f2bf(a1.x); Vs[vd0+ 5][vkey]=f2bf(a1.y);
            Vs[vd0+ 6][vkey]=f2bf(a1.z); Vs[vd0+ 7][vkey]=f2bf(a1.w);
            Vs[vd0+ 8][vkey]=f2bf(a2.x); Vs[vd0+ 9][vkey]=f2bf(a2.y);
            Vs[vd0+10][vkey]=f2bf(a2.z); Vs[vd0+11][vkey]=f2bf(a2.w);
            Vs[vd0+12][vkey]=f2bf(a3.x); Vs[vd0+13][vkey]=f2bf(a3.y);
            Vs[vd0+14][vkey]=f2bf(a3.z); Vs[vd0+15][vkey]=f2bf(a3.w);
        }
        __syncthreads();

        // ---- S[16q x 64keys] = Q K^T (scaled) ----
        floatx4 S[4];
#pragma unroll
        for (int ct = 0; ct < 4; ++ct) S[ct] = (floatx4){0.f, 0.f, 0.f, 0.f};
#pragma unroll
        for (int ct = 0; ct < 4; ++ct) {
#pragma unroll
            for (int ks = 0; ks < 2; ++ks) {
                short8 kf = *(const short8*)(&Ks[ct * 16 + fr][ks * 32 + quad * 8]);
                S[ct] = __builtin_amdgcn_mfma_f32_16x16x32_bf16(qf[ks], kf, S[ct], 0, 0, 0);
            }
        }
        // causal mask: only the final chunk (t0 == PP + q0) is partially masked
        if (c == nchunks - 1) {
#pragma unroll
            for (int ct = 0; ct < 4; ++ct)
#pragma unroll
                for (int r = 0; r < 4; ++r)
                    if (ct * 16 + fr > wave * 16 + quad * 4 + r) S[ct][r] = -1e30f;
        }
        // ---- online softmax (rows live in 16-lane fr-groups, reg r) ----
#pragma unroll
        for (int r = 0; r < 4; ++r) {
            float mx = fmaxf(fmaxf(S[0][r], S[1][r]), fmaxf(S[2][r], S[3][r]));
#pragma unroll
            for (int o = 1; o <= 8; o <<= 1) mx = fmaxf(mx, __shfl_xor(mx, o, 64));
            float mnew = fmaxf(m_r[r], mx);
            float sum = 0.f;
#pragma unroll
            for (int ct = 0; ct < 4; ++ct) {
                float p = exp2f((S[ct][r] - mnew) * 1.44269504f);
                S[ct][r] = p;
                sum += p;
            }
#pragma unroll
            for (int o = 1; o <= 8; o <<= 1) sum += __shfl_xor(sum, o, 64);
            float alpha = exp2f((m_r[r] - mnew) * 1.44269504f);
            l_r[r] = l_r[r] * alpha + sum;
            m_r[r] = mnew;
#pragma unroll
            for (int c2 = 0; c2 < 4; ++c2) Oacc[c2][r] *= alpha;
        }
        // ---- P: C-layout -> A-layout via per-wave LDS ----
#pragma unroll
        for (int ct = 0; ct < 4; ++ct)
#pragma unroll
            for (int r = 0; r < 4; ++r)
                Ps[wave][quad * 4 + r][ct * 16 + fr] = f2bf(S[ct][r]);
        // (same-wave ds_write -> ds_read; compiler orders via lgkmcnt)
#pragma unroll
        for (int ks = 0; ks < 2; ++ks) {
            short8 pf = *(const short8*)(&Ps[wave][fr][ks * 32 + quad * 8]);
#pragma unroll
            for (int c2 = 0; c2 < 4; ++c2) {
                short8 vf = *(const short8*)(&Vs[c2 * 16 + fr][ks * 32 + quad * 8]);
                Oacc[c2] = __builtin_amdgcn_mfma_f32_16x16x32_bf16(pf, vf, Oacc[c2], 0, 0, 0);
            }
        }
    }
    // ---- epilogue: O / l -> am stash (v-past region) ----
#pragma unroll
    for (int r = 0; r < 4; ++r) {
        float inv = 1.f / l_r[r];
        int q = q0 + wave * 16 + quad * 4 + r;
        float* dst = present + VOFF + (bhNS + q) * DD;
#pragma unroll
        for (int c2 = 0; c2 < 4; ++c2) dst[c2 * 16 + fr] = Oacc[c2][r] * inv;
    }
}

// ---------------- final: copy layer_past into present's past slots ----------------
__global__ __launch_bounds__(256) void copy_past_k(
    const float* __restrict__ past,
    float* __restrict__ present)
{
    int idx = blockIdx.x * 256 + threadIdx.x;
    size_t e0 = (size_t)idx * 8;
    int r = (int)(e0 >> 6);
    int off = (int)(e0 & 63);
    int t = r & (PP - 1);
    int bh = r >> 10;
    size_t dstoff = (((size_t)bh * NS) + t) * DD + off;
    *(float4*)(present + dstoff)     = *(const float4*)(past + e0);
    *(float4*)(present + dstoff + 4) = *(const float4*)(past + e0 + 4);
}

extern "C" void kernel_launch(void* const* d_in, const int* in_sizes, int n_in,
                              void* d_out, int out_size, void* d_ws, size_t ws_size,
                              hipStream_t stream) {
    const float* x      = (const float*)d_in[0];
    const float* past   = (const float*)d_in[1];
    const float* w_attn = (const float*)d_in[2];
    const float* b_attn = (const float*)d_in[3];
    const float* w_proj = (const float*)d_in[4];
    const float* b_proj = (const float*)d_in[5];
    float* out = (float*)d_out;
    float* present = out + (size_t)BB * SS * EE;

    gemm_k<0><<<dim3(BB * SS / 64, E3 / 64), 256, 0, stream>>>(x, w_attn, b_attn, present, E3, EE);
    flash_attn_k<<<BB * HH * (SS / 64), 256, 0, stream>>>(past, present);
    gemm_k<1><<<dim3(BB * SS / 64, EE / 64), 256, 0, stream>>>(present, w_proj, b_proj, out, EE, EE);
    copy_past_k<<<(2 * BB * HH * PP * DD) / (256 * 8), 256, 0, stream>>>(past, present);
}